// Round 4
// baseline (275.926 us; speedup 1.0000x reference)
//
#include <hip/hip_runtime.h>
#include <stdint.h>

// Three-phase fused causal linear attention (B=4 H=16 T=2048 D=128, fp32 io):
//   out[b,h,i,:] = sum_{j<=i} (q_i . k_j) * v_j
// A1 k_cstate (1024 blocks, (bh,c), parallel): S_c = K_c^T V_c, bf16,
//    written to ws in the MFMA B-fragment layout (verified reader mapping).
// A2 k_prefix (512 blocks): in-place exclusive prefix over the 16 records
//    per bh (fp32 accumulate of bf16 partials).  Record 0 becomes zeros.
// B  k_out (1024 blocks, (bh,c), parallel): O_c = Q_c @ S_pre(c)
//    + tril(Q_c K_c^T) @ V_c.  Round-1 streaming structure (measured best:
//    one live score tile -> Ps LDS; Sb staged in LDS) with Sb staged by
//    async global_load_lds that lands under the Q/K/V register staging.
// ws usage: 64*16 records * 16384 shorts * 2B = 32 MiB.
#define SEQ    2048
#define DIM    128
#define CHUNK  128
#define NCHUNK 16
#define NBH    64
#define RECSH  16384        // shorts per (bh,c) state record

typedef __attribute__((ext_vector_type(8))) short short8;   // 8 bf16
typedef __attribute__((ext_vector_type(4))) float floatx4;  // MFMA acc

#define MFMA(a, b, c) __builtin_amdgcn_mfma_f32_16x16x32_bf16((a), (b), (c), 0, 0, 0)

__device__ __forceinline__ short f2bf(float f) {
  union { float f; uint32_t u; } x; x.f = f;
  uint32_t r = x.u + 0x7fffu + ((x.u >> 16) & 1u);   // RNE
  return (short)(r >> 16);
}
__device__ __forceinline__ float bf2f(short s) {
  union { uint32_t u; float f; } x;
  x.u = ((uint32_t)(uint16_t)s) << 16;
  return x.f;
}
__device__ __forceinline__ short8 pack8(const float4 a, const float4 b) {
  short8 s;
  s[0] = f2bf(a.x); s[1] = f2bf(a.y); s[2] = f2bf(a.z); s[3] = f2bf(a.w);
  s[4] = f2bf(b.x); s[5] = f2bf(b.y); s[6] = f2bf(b.z); s[7] = f2bf(b.w);
  return s;
}
// async 16B HBM->LDS; dest must be wave-uniform base + lane*16.
__device__ __forceinline__ void gload16(const void* g, void* l) {
  __builtin_amdgcn_global_load_lds(
      (const __attribute__((address_space(1))) void*)g,
      (__attribute__((address_space(3))) void*)l, 16, 0, 0);
}

// ---------------------------------------------------------------------------
// A1: per-chunk state S_c = K_c^T V_c (full 128x128), bf16 frag layout.
// Wave w owns d'-tile w (cols 16w..16w+15), all 8 d-tiles (acc[8]).
__global__ __launch_bounds__(512, 2) void k_cstate(
    const float* __restrict__ kin, const float* __restrict__ vin,
    short* __restrict__ ws) {
  const int blk = blockIdx.x;
  const int bh  = blk & 63;              // bh%8 -> XCD, shared with A2/B
  const int c   = blk >> 6;
  const size_t base = (size_t)bh * SEQ * DIM + (size_t)c * CHUNK * DIM;
  const float* kc = kin + base;
  const float* vc = vin + base;

  __shared__ short Kt[128][136];   // K^T bf16: Kt[d'][j]; later reused as Ss
  __shared__ short Vt[128][136];   // V^T bf16: Vt[d][j]

  const int tid  = threadIdx.x;
  const int wave = tid >> 6;
  const int lane = tid & 63;
  const int q4   = lane >> 4;
  const int l16  = lane & 15;
  const int j    = tid & 127;
  const int dhi  = tid >> 7;

  // ---- stage K^T and V^T (coalesced b128 reads, scalar transposed writes)
#pragma unroll
  for (int it = 0; it < 4; ++it) {
    const int d0 = it * 32 + dhi * 8;
    const float* krow = kc + (size_t)j * DIM + d0;
    const float4 ka = *(const float4*)krow;
    const float4 kb2 = *(const float4*)(krow + 4);
    Kt[d0 + 0][j] = f2bf(ka.x); Kt[d0 + 1][j] = f2bf(ka.y);
    Kt[d0 + 2][j] = f2bf(ka.z); Kt[d0 + 3][j] = f2bf(ka.w);
    Kt[d0 + 4][j] = f2bf(kb2.x); Kt[d0 + 5][j] = f2bf(kb2.y);
    Kt[d0 + 6][j] = f2bf(kb2.z); Kt[d0 + 7][j] = f2bf(kb2.w);
    const float* vrow = vc + (size_t)j * DIM + d0;
    const float4 va = *(const float4*)vrow;
    const float4 vb2 = *(const float4*)(vrow + 4);
    Vt[d0 + 0][j] = f2bf(va.x); Vt[d0 + 1][j] = f2bf(va.y);
    Vt[d0 + 2][j] = f2bf(va.z); Vt[d0 + 3][j] = f2bf(va.w);
    Vt[d0 + 4][j] = f2bf(vb2.x); Vt[d0 + 5][j] = f2bf(vb2.y);
    Vt[d0 + 6][j] = f2bf(vb2.z); Vt[d0 + 7][j] = f2bf(vb2.w);
  }
  __syncthreads();

  // ---- S^T[d][d'] = sum_j V^T[d][j] K[j][d']  (same frags as verified scan)
  floatx4 acc[8];
#pragma unroll
  for (int m = 0; m < 8; ++m)
#pragma unroll
    for (int r = 0; r < 4; ++r) acc[m][r] = 0.f;
#pragma unroll
  for (int ks = 0; ks < 4; ++ks) {
    const short8 bk = *(const short8*)&Kt[wave * 16 + l16][ks * 32 + q4 * 8];
#pragma unroll
    for (int m = 0; m < 8; ++m) {
      const short8 av = *(const short8*)&Vt[m * 16 + l16][ks * 32 + q4 * 8];
      acc[m] = MFMA(av, bk, acc[m]);
    }
  }
  __syncthreads();                 // all Kt reads done; reuse as Ss

  // ---- dump acc -> Ss[d][d'] (bf16)
  short (*Ss)[136] = (short (*)[136])Kt;
#pragma unroll
  for (int m = 0; m < 8; ++m)
#pragma unroll
    for (int r = 0; r < 4; ++r)
      Ss[m * 16 + q4 * 4 + r][wave * 16 + l16] = f2bf(acc[m][r]);
  __syncthreads();

  // ---- copy Ss -> ws record in frag layout (vector 16B read + store).
  // Mapping matches the verified per-slice copy: t8 = dsl*512 + t',
  // row = dsl*32 + tnl*16 + l16x, col = ks2*32 + q4x*8, offset = t8*8.
  short* rec = ws + (size_t)(bh * NCHUNK + c) * RECSH;
#pragma unroll
  for (int i = 0; i < 4; ++i) {
    const int t8  = i * 512 + tid;
    const int row = ((t8 >> 9) << 5) + (((t8 >> 6) & 1) << 4) + (t8 & 15);
    const int col = (((t8 >> 7) & 3) << 5) + (((t8 >> 4) & 3) << 3);
    *(short8*)&rec[(size_t)t8 * 8] = *(const short8*)&Ss[row][col];
  }
}

// ---------------------------------------------------------------------------
// A2: in-place exclusive prefix over the 16 records of each bh.
// Grid 512 = 64 bh x 8 parts; each thread owns 8 shorts of the record.
__global__ __launch_bounds__(256, 4) void k_prefix(short* __restrict__ ws) {
  const int blk = blockIdx.x;
  const int bh  = blk & 63;              // bh%8 -> XCD, shared with A1/B
  const int p   = blk >> 6;
  const int off = p * 2048 + threadIdx.x * 8;
  short* wb = ws + (size_t)bh * NCHUNK * RECSH;

  float run[8];
#pragma unroll
  for (int s = 0; s < 8; ++s) run[s] = 0.f;
#pragma unroll
  for (int cc = 0; cc < NCHUNK; ++cc) {
    short8* ptr = (short8*)&wb[(size_t)cc * RECSH + off];
    const short8 rv = *ptr;              // read partial S_cc
    short8 ov;
#pragma unroll
    for (int s = 0; s < 8; ++s) ov[s] = f2bf(run[s]);
    *ptr = ov;                           // write exclusive prefix (c=0 -> 0)
#pragma unroll
    for (int s = 0; s < 8; ++s) run[s] += bf2f(rv[s]);
  }
}

// ---------------------------------------------------------------------------
// B: one block per (bh, chunk).  Round-1 streaming structure (measured
// fastest): one live score tile -> Ps, Sb in LDS.  Sb staged async.
__global__ __launch_bounds__(512, 2) void k_out(
    const float* __restrict__ qin, const float* __restrict__ kin,
    const float* __restrict__ vin, const short* __restrict__ ws,
    float* __restrict__ out) {
  const int blk = blockIdx.x;
  const int bh  = blk & 63;              // bh%8 -> XCD, shared with A1/A2
  const int c   = blk >> 6;
  const size_t base = (size_t)bh * SEQ * DIM + (size_t)c * CHUNK * DIM;
  const float* qc = qin + base;
  const float* kc = kin + base;
  const float* vc = vin + base;
  float* oc = out + base;

  __shared__ short Klds[128][136];  // K chunk bf16 row-major
  __shared__ short Vt[128][136];    // V^T: Vt[d][j]
  __shared__ short Ps[128][136];    // masked scores: Ps[i_loc][j]
  __shared__ __align__(16) short Sb[RECSH];  // S_pre frag blob

  const int tid  = threadIdx.x;
  const int wave = tid >> 6;
  const int lane = tid & 63;
  const int q4   = lane >> 4;
  const int l16  = lane & 15;
  const int j    = tid & 127;
  const int dhi  = tid >> 7;

  // ---- issue async Sb landing first (lands under the staging below)
  const short* sp = ws + (size_t)(bh * NCHUNK + c) * RECSH;
#pragma unroll
  for (int i = 0; i < 4; ++i) {
    const int g = i * 512 + tid;         // wave-uniform base + lane*16
    gload16(&sp[(size_t)g * 8], &Sb[(size_t)g * 8]);
  }

  // ---- Q fragments straight to registers
  const float* qrow = qc + (size_t)(wave * 16 + l16) * DIM + q4 * 8;
  short8 aq[4];
#pragma unroll
  for (int ks = 0; ks < 4; ++ks)
    aq[ks] = pack8(*(const float4*)(qrow + ks * 32),
                   *(const float4*)(qrow + ks * 32 + 4));

  // ---- stage K row-major bf16 (vector b128 stores)
#pragma unroll
  for (int it = 0; it < 4; ++it) {
    const int e = it * 4096 + tid * 8;
    *(short8*)&Klds[e >> 7][e & 127] =
        pack8(*(const float4*)(kc + e), *(const float4*)(kc + e + 4));
  }
  // ---- stage V^T (scalar transposed writes, row-consecutive lanes)
#pragma unroll
  for (int it = 0; it < 4; ++it) {
    const int d0 = it * 32 + dhi * 8;
    const float* vrow = vc + (size_t)j * DIM + d0;
    const float4 a = *(const float4*)vrow;
    const float4 b = *(const float4*)(vrow + 4);
    Vt[d0 + 0][j] = f2bf(a.x); Vt[d0 + 1][j] = f2bf(a.y);
    Vt[d0 + 2][j] = f2bf(a.z); Vt[d0 + 3][j] = f2bf(a.w);
    Vt[d0 + 4][j] = f2bf(b.x); Vt[d0 + 5][j] = f2bf(b.y);
    Vt[d0 + 6][j] = f2bf(b.z); Vt[d0 + 7][j] = f2bf(b.w);
  }
  __syncthreads();   // drains vmcnt: Sb landed; Klds/Vt visible

  floatx4 oacc[8];
#pragma unroll
  for (int tn = 0; tn < 8; ++tn)
#pragma unroll
    for (int r = 0; r < 4; ++r) oacc[tn][r] = 0.f;

  // ---- inter-chunk part: O += Q @ S_pre (B-frags from Sb; c=0 reads zeros)
#pragma unroll
  for (int ks = 0; ks < 4; ++ks)
#pragma unroll
    for (int tn = 0; tn < 8; ++tn) {
      const short8 bs = *(const short8*)
          &Sb[(tn >> 1) * 4096 + ks * 1024 + (tn & 1) * 512 + lane * 8];
      oacc[tn] = MFMA(aq[ks], bs, oacc[tn]);
    }

  // ---- intra-chunk causal scores for i-tile `wave` (one live tile)
  for (int tj = 0; tj <= wave; ++tj) {
    floatx4 sacc;
#pragma unroll
    for (int r = 0; r < 4; ++r) sacc[r] = 0.f;
#pragma unroll
    for (int ks = 0; ks < 4; ++ks) {
      const short8 bk = *(const short8*)&Klds[tj * 16 + l16][ks * 32 + q4 * 8];
      sacc = MFMA(aq[ks], bk, sacc);
    }
#pragma unroll
    for (int r = 0; r < 4; ++r) {
      float val = sacc[r];
      if (tj == wave && l16 > q4 * 4 + r) val = 0.f;   // strict-upper mask
      Ps[wave * 16 + q4 * 4 + r][tj * 16 + l16] = f2bf(val);
    }
  }
  if ((wave & 1) == 0) {   // even wave: zero tile wave+1 (PV k-step pad)
#pragma unroll
    for (int r = 0; r < 4; ++r)
      Ps[wave * 16 + q4 * 4 + r][(wave + 1) * 16 + l16] = 0;
  }

  // ---- PV: same-wave Ps rows (no barrier needed)
  const int kst = (wave + 2) >> 1;
  for (int t = 0; t < kst; ++t) {
    const short8 ap = *(const short8*)&Ps[wave * 16 + l16][t * 32 + q4 * 8];
#pragma unroll
    for (int tn = 0; tn < 8; ++tn) {
      const short8 bv = *(const short8*)&Vt[tn * 16 + l16][t * 32 + q4 * 8];
      oacc[tn] = MFMA(ap, bv, oacc[tn]);
    }
  }

  // ---- write out tile (fp32)
#pragma unroll
  for (int tn = 0; tn < 8; ++tn)
#pragma unroll
    for (int r = 0; r < 4; ++r)
      oc[(size_t)(wave * 16 + q4 * 4 + r) * DIM + tn * 16 + l16] = oacc[tn][r];
}

// ---------------------------------------------------------------------------
extern "C" void kernel_launch(void* const* d_in, const int* in_sizes, int n_in,
                              void* d_out, int out_size, void* d_ws, size_t ws_size,
                              hipStream_t stream) {
  const float* q = (const float*)d_in[0];
  const float* k = (const float*)d_in[1];
  const float* v = (const float*)d_in[2];
  float* out = (float*)d_out;
  (void)in_sizes; (void)n_in; (void)out_size; (void)ws_size;
  // requires ws_size >= 64*16*16384*2 = 32 MiB
  short* ws = (short*)d_ws;

  hipLaunchKernelGGL(k_cstate, dim3(NBH * NCHUNK), dim3(512), 0, stream,
                     k, v, ws);
  hipLaunchKernelGGL(k_prefix, dim3(NBH * 8), dim3(256), 0, stream, ws);
  hipLaunchKernelGGL(k_out, dim3(NBH * NCHUNK), dim3(512), 0, stream,
                     q, k, v, ws, out);
}